// Round 2
// baseline (397.517 us; speedup 1.0000x reference)
//
#include <hip/hip_runtime.h>
#include <hip/hip_bf16.h>

#define B_ 16
#define C_ 512
#define N_ 2048
#define MID_ 256
#define EPS_ 1e-5f

typedef __attribute__((ext_vector_type(8))) short bf16x8;
typedef __attribute__((ext_vector_type(4))) float f32x4;
typedef __attribute__((ext_vector_type(8))) unsigned short us8;
typedef __attribute__((ext_vector_type(4))) unsigned short us4;

static __device__ __forceinline__ float bf2f(unsigned short u) {
    union { unsigned int i; float f; } c; c.i = ((unsigned int)u) << 16; return c.f;
}
static __device__ __forceinline__ unsigned short f2bf(float f) {
    __hip_bfloat16 h = __float2bfloat16(f);
    return *reinterpret_cast<unsigned short*>(&h);
}
static __device__ __forceinline__ us8 pack8(float4 a, float4 b) {
    us8 r;
    r[0] = f2bf(a.x); r[1] = f2bf(a.y); r[2] = f2bf(a.z); r[3] = f2bf(a.w);
    r[4] = f2bf(b.x); r[5] = f2bf(b.y); r[6] = f2bf(b.z); r[7] = f2bf(b.w);
    return r;
}

// ---------------------------------------------------------------------------
// prep_x: x fp32 [B][C][N] -> xt bf16 [B][N][C]  (transpose + convert)
// ---------------------------------------------------------------------------
__global__ __launch_bounds__(256) void prep_x_kernel(
    const float* __restrict__ x, unsigned short* __restrict__ xt)
{
    const int b  = blockIdx.z;
    const int c0 = blockIdx.y * 64;
    const int n0 = blockIdx.x * 64;
    __shared__ unsigned short Ts[64][72];

    const int tid = threadIdx.x;
    const int cc  = tid >> 2;
    const int cq  = (tid & 3) * 4;

    #pragma unroll
    for (int i = 0; i < 4; i++) {
        float4 f = *(const float4*)&x[((size_t)b * C_ + c0 + cc) * N_ + n0 + cq + 16 * i];
        Ts[cq + 16 * i + 0][cc] = f2bf(f.x);
        Ts[cq + 16 * i + 1][cc] = f2bf(f.y);
        Ts[cq + 16 * i + 2][cc] = f2bf(f.z);
        Ts[cq + 16 * i + 3][cc] = f2bf(f.w);
    }
    __syncthreads();

    const int nn = tid >> 2;
    const int cg = (tid & 3) * 16;
    #pragma unroll
    for (int i = 0; i < 2; i++)
        *(us8*)&xt[((size_t)b * N_ + n0 + nn) * C_ + c0 + cg + 8 * i] =
            *(const us8*)&Ts[nn][cg + 8 * i];
}

// ---------------------------------------------------------------------------
// prep_w: wq/wk/wv fp32 [256][512] -> wb bf16 [3][256][512]
// ---------------------------------------------------------------------------
__global__ __launch_bounds__(256) void prep_w_kernel(
    const float* __restrict__ wq, const float* __restrict__ wk,
    const float* __restrict__ wv, unsigned short* __restrict__ wb)
{
    const int nthr = gridDim.x * 256;
    for (int u = blockIdx.x * 256 + threadIdx.x; u < 98304; u += nthr) {
        int p = u >> 15;
        int o4 = u & 32767;
        const float* src = (p == 0) ? wq : (p == 1) ? wk : wv;
        float4 f = *(const float4*)&src[o4 * 4];
        us4 r;
        r[0] = f2bf(f.x); r[1] = f2bf(f.y); r[2] = f2bf(f.z); r[3] = f2bf(f.w);
        *(us4*)&wb[(size_t)p * 131072 + o4 * 4] = r;
    }
}

// ---------------------------------------------------------------------------
// qkv_gemm (MFMA): out = W[256,512] x x_b[512,2048] per (b, p).
// q is stored PRE-SCALED by 1/16 (= 1/sqrt(MID); exact power-of-2 in bf16).
// ---------------------------------------------------------------------------
__global__ __launch_bounds__(256) void qkv_gemm_kernel(
    const unsigned short* __restrict__ xt, const unsigned short* __restrict__ wb,
    const float* __restrict__ bq, const float* __restrict__ gq,
    const float* __restrict__ betaq, const float* __restrict__ mq,
    const float* __restrict__ vq,
    const float* __restrict__ bk, const float* __restrict__ gk,
    const float* __restrict__ betak, const float* __restrict__ mk,
    const float* __restrict__ vk,
    const float* __restrict__ bv,
    unsigned short* __restrict__ qt, unsigned short* __restrict__ kt,
    unsigned short* __restrict__ v)
{
    const int p  = blockIdx.z % 3;
    const int b  = blockIdx.z / 3;
    const int n0 = blockIdx.x * 128;
    const int m0 = blockIdx.y * 128;

    __shared__ unsigned short Ws[128][72];
    __shared__ unsigned short Xs[128][72];
    __shared__ float sc_s[128], of_s[128];

    const int tid  = threadIdx.x;
    const int wave = tid >> 6;
    const int lane = tid & 63;
    const int quad = lane >> 4;
    const int l16  = lane & 15;
    const int wi   = wave >> 1;
    const int wj   = wave & 1;

    const unsigned short* wbp = wb + (size_t)p * 131072;
    const unsigned short* xtb = xt + (size_t)b * N_ * C_;

    if (tid < 128) {
        int m = m0 + tid;
        if (p == 0) {
            float inv = gq[m] * rsqrtf(vq[m] + EPS_);
            // fold 1/16 score scale into q (ReLU commutes with positive scale)
            sc_s[tid] = inv * 0.0625f;
            of_s[tid] = ((bq[m] - mq[m]) * inv + betaq[m]) * 0.0625f;
        } else if (p == 1) {
            float inv = gk[m] * rsqrtf(vk[m] + EPS_);
            sc_s[tid] = inv; of_s[tid] = (bk[m] - mk[m]) * inv + betak[m];
        } else {
            sc_s[tid] = 1.0f; of_s[tid] = bv[m];
        }
    }

    unsigned short (*Asrc)[72] = (p == 2) ? Xs : Ws;
    unsigned short (*Bsrc)[72] = (p == 2) ? Ws : Xs;

    f32x4 acc[4][4];
    #pragma unroll
    for (int it = 0; it < 4; it++)
        #pragma unroll
        for (int jt = 0; jt < 4; jt++)
            #pragma unroll
            for (int r = 0; r < 4; r++) acc[it][jt][r] = 0.0f;

    const int srow  = tid >> 1;
    const int shalf = (tid & 1) * 32;

    for (int k0 = 0; k0 < C_; k0 += 64) {
        __syncthreads();
        #pragma unroll
        for (int i = 0; i < 4; i++) {
            *(us8*)&Ws[srow][shalf + 8 * i] =
                *(const us8*)&wbp[(size_t)(m0 + srow) * C_ + k0 + shalf + 8 * i];
            *(us8*)&Xs[srow][shalf + 8 * i] =
                *(const us8*)&xtb[(size_t)(n0 + srow) * C_ + k0 + shalf + 8 * i];
        }
        __syncthreads();
        #pragma unroll
        for (int cl = 0; cl < 64; cl += 32) {
            bf16x8 af[4], bfr[4];
            #pragma unroll
            for (int t = 0; t < 4; t++)
                af[t] = *(const bf16x8*)&Asrc[wi * 64 + t * 16 + l16][cl + quad * 8];
            #pragma unroll
            for (int t = 0; t < 4; t++)
                bfr[t] = *(const bf16x8*)&Bsrc[wj * 64 + t * 16 + l16][cl + quad * 8];
            #pragma unroll
            for (int it = 0; it < 4; it++)
                #pragma unroll
                for (int jt = 0; jt < 4; jt++)
                    acc[it][jt] = __builtin_amdgcn_mfma_f32_16x16x32_bf16(
                        af[it], bfr[jt], acc[it][jt], 0, 0, 0);
        }
    }
    __syncthreads();

    if (p < 2) {
        unsigned short* outT = (p == 0) ? qt : kt;
        #pragma unroll
        for (int it = 0; it < 4; it++) {
            int ml = wi * 64 + it * 16 + quad * 4;
            #pragma unroll
            for (int jt = 0; jt < 4; jt++) {
                int n = n0 + wj * 64 + jt * 16 + l16;
                us4 pk;
                #pragma unroll
                for (int r = 0; r < 4; r++) {
                    float val = acc[it][jt][r] * sc_s[ml + r] + of_s[ml + r];
                    pk[r] = f2bf(fmaxf(val, 0.0f));
                }
                *(us4*)&outT[((size_t)b * N_ + n) * MID_ + m0 + ml] = pk;
            }
        }
    } else {
        #pragma unroll
        for (int it = 0; it < 4; it++) {
            int nl = n0 + wi * 64 + it * 16 + quad * 4;
            #pragma unroll
            for (int jt = 0; jt < 4; jt++) {
                int mloc = wj * 64 + jt * 16 + l16;
                float off = of_s[mloc];
                us4 pk;
                #pragma unroll
                for (int r = 0; r < 4; r++)
                    pk[r] = f2bf(acc[it][jt][r] + off);
                *(us4*)&v[((size_t)b * MID_ + m0 + mloc) * N_ + nl] = pk;
            }
        }
    }
}

// ---------------------------------------------------------------------------
// flash v4: latency-focused. Register-prefetched V (double-buffered, issued a
// full region ahead, kept in flight ACROSS the barrier) and Q (issued at
// region top, consumed after PV). Raw s_barrier + lgkmcnt(0)-only wait so
// outstanding global loads survive the barrier (HIP __syncthreads would drain
// vmcnt(0) and serialize the pipeline). K register cache dropped (R1 showed
// LDS throughput is not the binding constraint) to pay for prefetch VGPRs.
// ---------------------------------------------------------------------------
#define LGKM_BARRIER() do { \
    asm volatile("s_waitcnt lgkmcnt(0)" ::: "memory"); \
    __builtin_amdgcn_s_barrier(); \
} while (0)

#define REGION(R, VC, VN) do { \
    const int i0_ = (R) * 64; \
    /* issue V(R+1) prefetch into VN (consumed next region, across barrier) */ \
    _Pragma("unroll") \
    for (int u_ = 0; u_ < 8; u_++) \
        VN[u_] = *(const bf16x8*)(vbase + (size_t)((u_ >> 1) * 16) * N_ + \
                                  i0_ + 64 + (u_ & 1) * 32); \
    /* issue Q(R+1) (consumed in S after PV below) */ \
    _Pragma("unroll") \
    for (int c_ = 0; c_ < 8; c_++) \
        qf[c_] = *(const bf16x8*)(qbase + (size_t)(i0_ + 64) * MID_ + c_ * 32); \
    __builtin_amdgcn_sched_barrier(0); \
    /* PV(R): O += V(R) P(R), V from registers (prefetched last region) */ \
    _Pragma("unroll") \
    for (int ic_ = 0; ic_ < 64; ic_ += 32) { \
        bf16x8 pb[4]; \
        _Pragma("unroll") \
        for (int jt_ = 0; jt_ < 4; jt_++) \
            pb[jt_] = *(const bf16x8*)&Ps[(R) & 1][jt_ * 16 + l16][ic_ + quad * 8]; \
        _Pragma("unroll") \
        for (int ct_ = 0; ct_ < 4; ct_++) { \
            _Pragma("unroll") \
            for (int jt_ = 0; jt_ < 4; jt_++) \
                O[ct_][jt_] = __builtin_amdgcn_mfma_f32_16x16x32_bf16( \
                    VC[ct_ * 2 + (ic_ >> 5)], pb[jt_], O[ct_][jt_], 0, 0, 0); \
        } \
    } \
    /* S(R+1) = Q(R+1) K^T */ \
    f32x4 S[4]; \
    _Pragma("unroll") \
    for (int jt_ = 0; jt_ < 4; jt_++) \
        _Pragma("unroll") \
        for (int r_ = 0; r_ < 4; r_++) S[jt_][r_] = 0.0f; \
    _Pragma("unroll") \
    for (int c_ = 0; c_ < 8; c_++) { \
        bf16x8 a_ = qf[c_]; \
        _Pragma("unroll") \
        for (int jt_ = 0; jt_ < 4; jt_++) { \
            bf16x8 b_ = *(const bf16x8*)&Ks[jt_ * 16 + l16][c_ * 32 + quad * 8]; \
            S[jt_] = __builtin_amdgcn_mfma_f32_16x16x32_bf16(a_, b_, S[jt_], 0, 0, 0); \
        } \
    } \
    /* exp -> P(R+1) into other buffer */ \
    _Pragma("unroll") \
    for (int jt_ = 0; jt_ < 4; jt_++) { \
        us4 pk; \
        _Pragma("unroll") \
        for (int r_ = 0; r_ < 4; r_++) { \
            float e_ = __expf(S[jt_][r_]); \
            psum[jt_] += e_; \
            pk[r_] = f2bf(e_); \
        } \
        *(us4*)&Ps[((R) & 1) ^ 1][jt_ * 16 + l16][wave * 16 + quad * 4] = pk; \
    } \
    LGKM_BARRIER(); \
} while (0)

__global__ __launch_bounds__(256, 2) void flash_kernel(
    const unsigned short* __restrict__ qt,   // [B][N][MID], pre-scaled 1/16
    const unsigned short* __restrict__ kt,   // [B][N][MID]
    const unsigned short* __restrict__ v,    // [B][MID][N]
    unsigned short* __restrict__ ctxT)       // [B][N][MID]
{
    const int b  = blockIdx.y;
    const int j0 = blockIdx.x * 64;

    __shared__ unsigned short Ks[64][264];     // [j][c] persistent, 33 KB
    __shared__ unsigned short Ps[2][64][72];   // double-buffered P, 18 KB
    __shared__ float red[4][64];

    const int tid  = threadIdx.x;
    const int wave = tid >> 6;
    const int lane = tid & 63;
    const int quad = lane >> 4;
    const int l16  = lane & 15;

    const unsigned short* qb = qt + (size_t)b * N_ * MID_;
    const unsigned short* kb = kt + (size_t)b * N_ * MID_;
    const unsigned short* vb = v  + (size_t)b * MID_ * N_;

    // ---- stage K into LDS (persistent) ----
    #pragma unroll
    for (int r = 0; r < 8; r++) {
        int ch = tid + r * 256;
        int j = ch >> 5, c8 = ch & 31;
        *(us8*)&Ks[j][c8 * 8] = *(const us8*)&kb[(size_t)(j0 + j) * MID_ + c8 * 8];
    }

    f32x4 O[4][4];
    #pragma unroll
    for (int ct = 0; ct < 4; ct++)
        #pragma unroll
        for (int jt = 0; jt < 4; jt++)
            #pragma unroll
            for (int r = 0; r < 4; r++) O[ct][jt][r] = 0.0f;
    float psum[4] = {0.0f, 0.0f, 0.0f, 0.0f};

    // per-wave base pointers (A-fragments from global)
    const unsigned short* qbase = qb + (size_t)(wave * 16 + l16) * MID_ + quad * 8;
    const unsigned short* vbase = vb + (size_t)(wave * 64 + l16) * N_ + quad * 8;

    bf16x8 vA[8], vB[8], qf[8];

    // issue Q(0) and V(0) loads (stay in flight across the Ks barrier)
    bf16x8 q0[8];
    #pragma unroll
    for (int c = 0; c < 8; c++)
        q0[c] = *(const bf16x8*)(qbase + c * 32);
    #pragma unroll
    for (int u = 0; u < 8; u++)
        vA[u] = *(const bf16x8*)(vbase + (size_t)((u >> 1) * 16) * N_ + (u & 1) * 32);

    LGKM_BARRIER();   // Ks visible (Q/V loads remain outstanding)

    // ---- prologue: S(0) -> P(0) into Ps[0] ----
    {
        f32x4 S[4];
        #pragma unroll
        for (int jt = 0; jt < 4; jt++)
            #pragma unroll
            for (int r = 0; r < 4; r++) S[jt][r] = 0.0f;

        #pragma unroll
        for (int c = 0; c < 8; c++) {
            bf16x8 a = q0[c];
            #pragma unroll
            for (int jt = 0; jt < 4; jt++) {
                bf16x8 bfr = *(const bf16x8*)&Ks[jt * 16 + l16][c * 32 + quad * 8];
                S[jt] = __builtin_amdgcn_mfma_f32_16x16x32_bf16(a, bfr, S[jt], 0, 0, 0);
            }
        }
        #pragma unroll
        for (int jt = 0; jt < 4; jt++) {
            us4 pk;
            #pragma unroll
            for (int r = 0; r < 4; r++) {
                float e = __expf(S[jt][r]);
                psum[jt] += e;
                pk[r] = f2bf(e);
            }
            // i = wave*16 + quad*4 + r (C/D row), j = jt*16 + l16 (C/D col)
            *(us4*)&Ps[0][jt * 16 + l16][wave * 16 + quad * 4] = pk;
        }
    }
    LGKM_BARRIER();

    // ---- main pipelined loop: regions 0..30, one barrier each ----
    for (int r = 0; r < 30; r += 2) {
        REGION(r,     vA, vB);
        REGION(r + 1, vB, vA);
    }
    REGION(30, vA, vB);

    // ---- epilogue: PV(31) from Ps[1], V(31) already in vB ----
    {
        #pragma unroll
        for (int ic = 0; ic < 64; ic += 32) {
            bf16x8 pb[4];
            #pragma unroll
            for (int jt = 0; jt < 4; jt++)
                pb[jt] = *(const bf16x8*)&Ps[1][jt * 16 + l16][ic + quad * 8];
            #pragma unroll
            for (int ct = 0; ct < 4; ct++) {
                #pragma unroll
                for (int jt = 0; jt < 4; jt++)
                    O[ct][jt] = __builtin_amdgcn_mfma_f32_16x16x32_bf16(
                        vB[ct * 2 + (ic >> 5)], pb[jt], O[ct][jt], 0, 0, 0);
            }
        }
    }

    // ---- single deferred denominator reduction ----
    #pragma unroll
    for (int jt = 0; jt < 4; jt++) {
        psum[jt] += __shfl_xor(psum[jt], 16, 64);
        psum[jt] += __shfl_xor(psum[jt], 32, 64);
    }
    __syncthreads();
    if (quad == 0)
        #pragma unroll
        for (int jt = 0; jt < 4; jt++) red[wave][jt * 16 + l16] = psum[jt];
    __syncthreads();

    float rl[4];
    #pragma unroll
    for (int jt = 0; jt < 4; jt++)
        rl[jt] = 1.0f / (red[0][jt * 16 + l16] + red[1][jt * 16 + l16] +
                         red[2][jt * 16 + l16] + red[3][jt * 16 + l16]);

    #pragma unroll
    for (int ct = 0; ct < 4; ct++) {
        #pragma unroll
        for (int jt = 0; jt < 4; jt++) {
            us4 pk;
            #pragma unroll
            for (int r = 0; r < 4; r++)
                pk[r] = f2bf(O[ct][jt][r] * rl[jt]);
            int j = j0 + jt * 16 + l16;
            *(us4*)&ctxT[((size_t)b * N_ + j) * MID_ + wave * 64 + ct * 16 + quad * 4] = pk;
        }
    }
}

// ---------------------------------------------------------------------------
// out_gemm (MFMA): out[b,co,n] = x + bo[co] + sum_m wo[co,m]*ctxT[b,n,m]
// ---------------------------------------------------------------------------
__global__ __launch_bounds__(256) void out_gemm_kernel(
    const float* __restrict__ wo, const float* __restrict__ bo,
    const unsigned short* __restrict__ ctxT, const float* __restrict__ x,
    float* __restrict__ out)
{
    const int b   = blockIdx.z;
    const int n0  = blockIdx.x * 128;
    const int co0 = blockIdx.y * 128;

    __shared__ unsigned short Wos[128][72];
    __shared__ unsigned short Cs[128][72];
    __shared__ float bo_s[128];

    const int tid  = threadIdx.x;
    const int wave = tid >> 6;
    const int lane = tid & 63;
    const int quad = lane >> 4;
    const int l16  = lane & 15;
    const int wi   = wave >> 1;
    const int wj   = wave & 1;

    if (tid < 128) bo_s[tid] = bo[co0 + tid];

    f32x4 acc[4][4];
    #pragma unroll
    for (int it = 0; it < 4; it++)
        #pragma unroll
        for (int jt = 0; jt < 4; jt++)
            #pragma unroll
            for (int r = 0; r < 4; r++) acc[it][jt][r] = 0.0f;

    const int srow  = tid >> 1;
    const int shalf = (tid & 1) * 32;

    for (int k0 = 0; k0 < MID_; k0 += 64) {
        __syncthreads();
        #pragma unroll
        for (int i = 0; i < 4; i++) {
            float4 f0 = *(const float4*)&wo[(size_t)(co0 + srow) * MID_ + k0 + shalf + 8 * i];
            float4 f1 = *(const float4*)&wo[(size_t)(co0 + srow) * MID_ + k0 + shalf + 8 * i + 4];
            *(us8*)&Wos[srow][shalf + 8 * i] = pack8(f0, f1);
            *(us8*)&Cs[srow][shalf + 8 * i] =
                *(const us8*)&ctxT[((size_t)b * N_ + n0 + srow) * MID_ + k0 + shalf + 8 * i];
        }
        __syncthreads();
        #pragma unroll
        for (int cl = 0; cl < 64; cl += 32) {
            bf16x8 af[4], bfr[4];
            #pragma unroll
            for (int t = 0; t < 4; t++)
                af[t] = *(const bf16x8*)&Wos[wi * 64 + t * 16 + l16][cl + quad * 8];
            #pragma unroll
            for (int t = 0; t < 4; t++)
                bfr[t] = *(const bf16x8*)&Cs[wj * 64 + t * 16 + l16][cl + quad * 8];
            #pragma unroll
            for (int it = 0; it < 4; it++)
                #pragma unroll
                for (int jt = 0; jt < 4; jt++)
                    acc[it][jt] = __builtin_amdgcn_mfma_f32_16x16x32_bf16(
                        af[it], bfr[jt], acc[it][jt], 0, 0, 0);
        }
    }
    __syncthreads();

    #pragma unroll
    for (int it = 0; it < 4; it++) {
        #pragma unroll
        for (int r = 0; r < 4; r++) {
            int col = wi * 64 + it * 16 + quad * 4 + r;
            int co = co0 + col;
            float bias = bo_s[col];
            #pragma unroll
            for (int jt = 0; jt < 4; jt++) {
                int n = n0 + wj * 64 + jt * 16 + l16;
                size_t a = ((size_t)b * C_ + co) * N_ + n;
                out[a] = acc[it][jt][r] + bias + x[a];
            }
        }
    }
}

extern "C" void kernel_launch(void* const* d_in, const int* in_sizes, int n_in,
                              void* d_out, int out_size, void* d_ws, size_t ws_size,
                              hipStream_t stream) {
    const float* x     = (const float*)d_in[0];
    const float* wq    = (const float*)d_in[1];
    const float* bq    = (const float*)d_in[2];
    const float* gq    = (const float*)d_in[3];
    const float* betaq = (const float*)d_in[4];
    const float* wk    = (const float*)d_in[5];
    const float* bk    = (const float*)d_in[6];
    const float* gk    = (const float*)d_in[7];
    const float* betak = (const float*)d_in[8];
    const float* wv    = (const float*)d_in[9];
    const float* bv    = (const float*)d_in[10];
    const float* wo    = (const float*)d_in[11];
    const float* bo    = (const float*)d_in[12];
    const float* mq    = (const float*)d_in[13];
    const float* vq    = (const float*)d_in[14];
    const float* mk    = (const float*)d_in[15];
    const float* vk    = (const float*)d_in[16];
    float* out = (float*)d_out;

    const size_t elems = (size_t)B_ * MID_ * N_;   // 8,388,608
    unsigned short* qt   = (unsigned short*)d_ws;  // [B][N][MID]
    unsigned short* kt   = qt + elems;             // [B][N][MID]
    unsigned short* v    = kt + elems;             // [B][MID][N]
    unsigned short* ctxT = v + elems;              // [B][N][MID]
    // workspace: 64 MiB

    // d_out doubles as scratch; dead before out_gemm writes the real output:
    unsigned short* xt = (unsigned short*)d_out;          // [B][N][C] = 32 MiB
    unsigned short* wb = xt + (size_t)B_ * N_ * C_;       // [3][256][512] = 768 KiB

    prep_x_kernel<<<dim3(N_ / 64, C_ / 64, B_), 256, 0, stream>>>(x, xt);
    prep_w_kernel<<<dim3(96), 256, 0, stream>>>(wq, wk, wv, wb);

    qkv_gemm_kernel<<<dim3(N_ / 128, MID_ / 128, B_ * 3), 256, 0, stream>>>(
        xt, wb, bq, gq, betaq, mq, vq, bk, gk, betak, mk, vk, bv, qt, kt, v);

    flash_kernel<<<dim3(N_ / 64, B_), 256, 0, stream>>>(qt, kt, v, ctxT);

    out_gemm_kernel<<<dim3(N_ / 128, C_ / 128, B_), 256, 0, stream>>>(
        wo, bo, ctxT, x, out);
}

// Round 3
// 369.856 us; speedup vs baseline: 1.0748x; 1.0748x over previous
//
#include <hip/hip_runtime.h>
#include <hip/hip_bf16.h>

#define B_ 16
#define C_ 512
#define N_ 2048
#define MID_ 256
#define EPS_ 1e-5f

typedef __attribute__((ext_vector_type(8))) short bf16x8;
typedef __attribute__((ext_vector_type(4))) float f32x4;
typedef __attribute__((ext_vector_type(8))) unsigned short us8;
typedef __attribute__((ext_vector_type(4))) unsigned short us4;

static __device__ __forceinline__ float bf2f(unsigned short u) {
    union { unsigned int i; float f; } c; c.i = ((unsigned int)u) << 16; return c.f;
}
static __device__ __forceinline__ unsigned short f2bf(float f) {
    __hip_bfloat16 h = __float2bfloat16(f);
    return *reinterpret_cast<unsigned short*>(&h);
}
static __device__ __forceinline__ us8 pack8(float4 a, float4 b) {
    us8 r;
    r[0] = f2bf(a.x); r[1] = f2bf(a.y); r[2] = f2bf(a.z); r[3] = f2bf(a.w);
    r[4] = f2bf(b.x); r[5] = f2bf(b.y); r[6] = f2bf(b.z); r[7] = f2bf(b.w);
    return r;
}

// ---------------------------------------------------------------------------
// prep_x: x fp32 [B][C][N] -> xt bf16 [B][N][C]  (transpose + convert)
// ---------------------------------------------------------------------------
__global__ __launch_bounds__(256) void prep_x_kernel(
    const float* __restrict__ x, unsigned short* __restrict__ xt)
{
    const int b  = blockIdx.z;
    const int c0 = blockIdx.y * 64;
    const int n0 = blockIdx.x * 64;
    __shared__ unsigned short Ts[64][72];

    const int tid = threadIdx.x;
    const int cc  = tid >> 2;
    const int cq  = (tid & 3) * 4;

    #pragma unroll
    for (int i = 0; i < 4; i++) {
        float4 f = *(const float4*)&x[((size_t)b * C_ + c0 + cc) * N_ + n0 + cq + 16 * i];
        Ts[cq + 16 * i + 0][cc] = f2bf(f.x);
        Ts[cq + 16 * i + 1][cc] = f2bf(f.y);
        Ts[cq + 16 * i + 2][cc] = f2bf(f.z);
        Ts[cq + 16 * i + 3][cc] = f2bf(f.w);
    }
    __syncthreads();

    const int nn = tid >> 2;
    const int cg = (tid & 3) * 16;
    #pragma unroll
    for (int i = 0; i < 2; i++)
        *(us8*)&xt[((size_t)b * N_ + n0 + nn) * C_ + c0 + cg + 8 * i] =
            *(const us8*)&Ts[nn][cg + 8 * i];
}

// ---------------------------------------------------------------------------
// prep_w: wq/wk/wv fp32 [256][512] -> wb bf16 [3][256][512]
// ---------------------------------------------------------------------------
__global__ __launch_bounds__(256) void prep_w_kernel(
    const float* __restrict__ wq, const float* __restrict__ wk,
    const float* __restrict__ wv, unsigned short* __restrict__ wb)
{
    const int nthr = gridDim.x * 256;
    for (int u = blockIdx.x * 256 + threadIdx.x; u < 98304; u += nthr) {
        int p = u >> 15;
        int o4 = u & 32767;
        const float* src = (p == 0) ? wq : (p == 1) ? wk : wv;
        float4 f = *(const float4*)&src[o4 * 4];
        us4 r;
        r[0] = f2bf(f.x); r[1] = f2bf(f.y); r[2] = f2bf(f.z); r[3] = f2bf(f.w);
        *(us4*)&wb[(size_t)p * 131072 + o4 * 4] = r;
    }
}

// ---------------------------------------------------------------------------
// qkv_gemm (MFMA): out = W[256,512] x x_b[512,2048] per (b, p).
// q is stored PRE-SCALED by 1/16 (= 1/sqrt(MID); exact power-of-2 in bf16).
// ---------------------------------------------------------------------------
__global__ __launch_bounds__(256) void qkv_gemm_kernel(
    const unsigned short* __restrict__ xt, const unsigned short* __restrict__ wb,
    const float* __restrict__ bq, const float* __restrict__ gq,
    const float* __restrict__ betaq, const float* __restrict__ mq,
    const float* __restrict__ vq,
    const float* __restrict__ bk, const float* __restrict__ gk,
    const float* __restrict__ betak, const float* __restrict__ mk,
    const float* __restrict__ vk,
    const float* __restrict__ bv,
    unsigned short* __restrict__ qt, unsigned short* __restrict__ kt,
    unsigned short* __restrict__ v)
{
    const int p  = blockIdx.z % 3;
    const int b  = blockIdx.z / 3;
    const int n0 = blockIdx.x * 128;
    const int m0 = blockIdx.y * 128;

    __shared__ unsigned short Ws[128][72];
    __shared__ unsigned short Xs[128][72];
    __shared__ float sc_s[128], of_s[128];

    const int tid  = threadIdx.x;
    const int wave = tid >> 6;
    const int lane = tid & 63;
    const int quad = lane >> 4;
    const int l16  = lane & 15;
    const int wi   = wave >> 1;
    const int wj   = wave & 1;

    const unsigned short* wbp = wb + (size_t)p * 131072;
    const unsigned short* xtb = xt + (size_t)b * N_ * C_;

    if (tid < 128) {
        int m = m0 + tid;
        if (p == 0) {
            float inv = gq[m] * rsqrtf(vq[m] + EPS_);
            // fold 1/16 score scale into q (ReLU commutes with positive scale)
            sc_s[tid] = inv * 0.0625f;
            of_s[tid] = ((bq[m] - mq[m]) * inv + betaq[m]) * 0.0625f;
        } else if (p == 1) {
            float inv = gk[m] * rsqrtf(vk[m] + EPS_);
            sc_s[tid] = inv; of_s[tid] = (bk[m] - mk[m]) * inv + betak[m];
        } else {
            sc_s[tid] = 1.0f; of_s[tid] = bv[m];
        }
    }

    unsigned short (*Asrc)[72] = (p == 2) ? Xs : Ws;
    unsigned short (*Bsrc)[72] = (p == 2) ? Ws : Xs;

    f32x4 acc[4][4];
    #pragma unroll
    for (int it = 0; it < 4; it++)
        #pragma unroll
        for (int jt = 0; jt < 4; jt++)
            #pragma unroll
            for (int r = 0; r < 4; r++) acc[it][jt][r] = 0.0f;

    const int srow  = tid >> 1;
    const int shalf = (tid & 1) * 32;

    for (int k0 = 0; k0 < C_; k0 += 64) {
        __syncthreads();
        #pragma unroll
        for (int i = 0; i < 4; i++) {
            *(us8*)&Ws[srow][shalf + 8 * i] =
                *(const us8*)&wbp[(size_t)(m0 + srow) * C_ + k0 + shalf + 8 * i];
            *(us8*)&Xs[srow][shalf + 8 * i] =
                *(const us8*)&xtb[(size_t)(n0 + srow) * C_ + k0 + shalf + 8 * i];
        }
        __syncthreads();
        #pragma unroll
        for (int cl = 0; cl < 64; cl += 32) {
            bf16x8 af[4], bfr[4];
            #pragma unroll
            for (int t = 0; t < 4; t++)
                af[t] = *(const bf16x8*)&Asrc[wi * 64 + t * 16 + l16][cl + quad * 8];
            #pragma unroll
            for (int t = 0; t < 4; t++)
                bfr[t] = *(const bf16x8*)&Bsrc[wj * 64 + t * 16 + l16][cl + quad * 8];
            #pragma unroll
            for (int it = 0; it < 4; it++)
                #pragma unroll
                for (int jt = 0; jt < 4; jt++)
                    acc[it][jt] = __builtin_amdgcn_mfma_f32_16x16x32_bf16(
                        af[it], bfr[jt], acc[it][jt], 0, 0, 0);
        }
    }
    __syncthreads();

    if (p < 2) {
        unsigned short* outT = (p == 0) ? qt : kt;
        #pragma unroll
        for (int it = 0; it < 4; it++) {
            int ml = wi * 64 + it * 16 + quad * 4;
            #pragma unroll
            for (int jt = 0; jt < 4; jt++) {
                int n = n0 + wj * 64 + jt * 16 + l16;
                us4 pk;
                #pragma unroll
                for (int r = 0; r < 4; r++) {
                    float val = acc[it][jt][r] * sc_s[ml + r] + of_s[ml + r];
                    pk[r] = f2bf(fmaxf(val, 0.0f));
                }
                *(us4*)&outT[((size_t)b * N_ + n) * MID_ + m0 + ml] = pk;
            }
        }
    } else {
        #pragma unroll
        for (int it = 0; it < 4; it++) {
            int nl = n0 + wi * 64 + it * 16 + quad * 4;
            #pragma unroll
            for (int jt = 0; jt < 4; jt++) {
                int mloc = wj * 64 + jt * 16 + l16;
                float off = of_s[mloc];
                us4 pk;
                #pragma unroll
                for (int r = 0; r < 4; r++)
                    pk[r] = f2bf(acc[it][jt][r] + off);
                *(us4*)&v[((size_t)b * MID_ + m0 + mloc) * N_ + nl] = pk;
            }
        }
    }
}

// ---------------------------------------------------------------------------
// flash v5: 8-wave (512-thread) blocks. Grid is fixed at 512 blocks (2/CU);
// the R1/R2 profiles showed everything idle (Mfma 19%, VALU 11%, HBM 14%) at
// 2 waves/SIMD -> latency-bound with no TLP. 8 waves/block doubles TLP to
// 4 waves/SIMD without changing traffic. Per-wave state shrinks (O 32 VGPR),
// i-tile=128 halves regions/barriers to 16/17. Loads are batched per phase
// (Q batch at S-start, V batch at PV-start) so each phase pays ~one latency,
// and live ranges don't overlap -> no spill (R2's failure: VGPR cap 128 +
// 13 MB scratch writes). launch_bounds(512,4) = 16 waves/CU cap 128 VGPR.
// ---------------------------------------------------------------------------
__global__ __launch_bounds__(512, 4) void flash_kernel(
    const unsigned short* __restrict__ qt,   // [B][N][MID], pre-scaled 1/16
    const unsigned short* __restrict__ kt,   // [B][N][MID]
    const unsigned short* __restrict__ v,    // [B][MID][N]
    unsigned short* __restrict__ ctxT)       // [B][N][MID]
{
    const int b  = blockIdx.y;
    const int j0 = blockIdx.x * 64;

    __shared__ unsigned short Ks[64][264];     // [j][c] persistent, 33.8 KB
    __shared__ unsigned short Ps[2][64][136];  // [j][i-tile 128], dbuf, 34.8 KB
    __shared__ float red[8][64];

    const int tid  = threadIdx.x;
    const int wave = tid >> 6;   // 0..7
    const int lane = tid & 63;
    const int quad = lane >> 4;
    const int l16  = lane & 15;

    const unsigned short* qb = qt + (size_t)b * N_ * MID_;
    const unsigned short* kb = kt + (size_t)b * N_ * MID_;
    const unsigned short* vb = v  + (size_t)b * MID_ * N_;

    // ---- stage K into LDS (persistent) ----
    #pragma unroll
    for (int r = 0; r < 4; r++) {
        int ch = tid + r * 512;
        int j = ch >> 5, c8 = ch & 31;
        *(us8*)&Ks[j][c8 * 8] = *(const us8*)&kb[(size_t)(j0 + j) * MID_ + c8 * 8];
    }
    __syncthreads();

    // O: wave owns c-rows [wave*32, +32) x all 64 j
    f32x4 O[2][4];
    #pragma unroll
    for (int ct = 0; ct < 2; ct++)
        #pragma unroll
        for (int jt = 0; jt < 4; jt++)
            #pragma unroll
            for (int r = 0; r < 4; r++) O[ct][jt][r] = 0.0f;
    float psum[4] = {0.0f, 0.0f, 0.0f, 0.0f};

    // S: wave owns i-rows [i0 + wave*16, +16)
    const unsigned short* qbase = qb + (size_t)(wave * 16 + l16) * MID_ + quad * 8;
    const unsigned short* vbase = vb + (size_t)(wave * 32 + l16) * N_ + quad * 8;

    // ---- prologue: S(0) -> P(0) into Ps[0] ----
    {
        f32x4 S[4];
        #pragma unroll
        for (int jt = 0; jt < 4; jt++)
            #pragma unroll
            for (int r = 0; r < 4; r++) S[jt][r] = 0.0f;

        bf16x8 qf[8];
        #pragma unroll
        for (int c = 0; c < 8; c++)
            qf[c] = *(const bf16x8*)(qbase + c * 32);
        #pragma unroll
        for (int c = 0; c < 8; c++) {
            #pragma unroll
            for (int jt = 0; jt < 4; jt++) {
                bf16x8 bfr = *(const bf16x8*)&Ks[jt * 16 + l16][c * 32 + quad * 8];
                S[jt] = __builtin_amdgcn_mfma_f32_16x16x32_bf16(qf[c], bfr, S[jt], 0, 0, 0);
            }
        }
        #pragma unroll
        for (int jt = 0; jt < 4; jt++) {
            us4 pk;
            #pragma unroll
            for (int r = 0; r < 4; r++) {
                float e = __expf(S[jt][r]);
                psum[jt] += e;
                pk[r] = f2bf(e);
            }
            // P row = j (jt*16+l16), col = i within tile (wave*16 + quad*4 + r)
            *(us4*)&Ps[0][jt * 16 + l16][wave * 16 + quad * 4] = pk;
        }
    }
    __syncthreads();

    // ---- main loop: 15 regions {S(t+1) || PV(t)}, one barrier each ----
    for (int t = 0; t < 15; t++) {
        const int i0  = t * 128;
        const int buf = t & 1;

        // S(t+1): Q batch load, MFMA vs persistent Ks, exp -> Ps[buf^1]
        {
            f32x4 S[4];
            #pragma unroll
            for (int jt = 0; jt < 4; jt++)
                #pragma unroll
                for (int r = 0; r < 4; r++) S[jt][r] = 0.0f;

            const unsigned short* qp = qbase + (size_t)(i0 + 128) * MID_;
            bf16x8 qf[8];
            #pragma unroll
            for (int c = 0; c < 8; c++)
                qf[c] = *(const bf16x8*)(qp + c * 32);
            #pragma unroll
            for (int c = 0; c < 8; c++) {
                #pragma unroll
                for (int jt = 0; jt < 4; jt++) {
                    bf16x8 bfr = *(const bf16x8*)&Ks[jt * 16 + l16][c * 32 + quad * 8];
                    S[jt] = __builtin_amdgcn_mfma_f32_16x16x32_bf16(qf[c], bfr, S[jt], 0, 0, 0);
                }
            }
            #pragma unroll
            for (int jt = 0; jt < 4; jt++) {
                us4 pk;
                #pragma unroll
                for (int r = 0; r < 4; r++) {
                    float e = __expf(S[jt][r]);
                    psum[jt] += e;
                    pk[r] = f2bf(e);
                }
                *(us4*)&Ps[buf ^ 1][jt * 16 + l16][wave * 16 + quad * 4] = pk;
            }
        }

        // PV(t): V batch load, O += V P from Ps[buf]
        {
            bf16x8 av[8];
            #pragma unroll
            for (int u = 0; u < 8; u++)   // u = ct*4 + (ic>>5)
                av[u] = *(const bf16x8*)(vbase + (size_t)((u >> 2) * 16) * N_ +
                                         i0 + (u & 3) * 32);
            #pragma unroll
            for (int ic = 0; ic < 128; ic += 32) {
                bf16x8 pb[4];
                #pragma unroll
                for (int jt = 0; jt < 4; jt++)
                    pb[jt] = *(const bf16x8*)&Ps[buf][jt * 16 + l16][ic + quad * 8];
                #pragma unroll
                for (int ct = 0; ct < 2; ct++)
                    #pragma unroll
                    for (int jt = 0; jt < 4; jt++)
                        O[ct][jt] = __builtin_amdgcn_mfma_f32_16x16x32_bf16(
                            av[ct * 4 + (ic >> 5)], pb[jt], O[ct][jt], 0, 0, 0);
            }
        }
        __syncthreads();
    }

    // ---- epilogue: PV(15) from Ps[1] ----
    {
        const int i0 = 15 * 128;
        bf16x8 av[8];
        #pragma unroll
        for (int u = 0; u < 8; u++)
            av[u] = *(const bf16x8*)(vbase + (size_t)((u >> 2) * 16) * N_ +
                                     i0 + (u & 3) * 32);
        #pragma unroll
        for (int ic = 0; ic < 128; ic += 32) {
            bf16x8 pb[4];
            #pragma unroll
            for (int jt = 0; jt < 4; jt++)
                pb[jt] = *(const bf16x8*)&Ps[1][jt * 16 + l16][ic + quad * 8];
            #pragma unroll
            for (int ct = 0; ct < 2; ct++)
                #pragma unroll
                for (int jt = 0; jt < 4; jt++)
                    O[ct][jt] = __builtin_amdgcn_mfma_f32_16x16x32_bf16(
                        av[ct * 4 + (ic >> 5)], pb[jt], O[ct][jt], 0, 0, 0);
        }
    }

    // ---- single deferred denominator reduction (8 waves) ----
    #pragma unroll
    for (int jt = 0; jt < 4; jt++) {
        psum[jt] += __shfl_xor(psum[jt], 16, 64);
        psum[jt] += __shfl_xor(psum[jt], 32, 64);
    }
    __syncthreads();
    if (quad == 0)
        #pragma unroll
        for (int jt = 0; jt < 4; jt++) red[wave][jt * 16 + l16] = psum[jt];
    __syncthreads();

    float rl[4];
    #pragma unroll
    for (int jt = 0; jt < 4; jt++) {
        float s = 0.0f;
        #pragma unroll
        for (int w = 0; w < 8; w++) s += red[w][jt * 16 + l16];
        rl[jt] = 1.0f / s;
    }

    #pragma unroll
    for (int ct = 0; ct < 2; ct++) {
        #pragma unroll
        for (int jt = 0; jt < 4; jt++) {
            us4 pk;
            #pragma unroll
            for (int r = 0; r < 4; r++)
                pk[r] = f2bf(O[ct][jt][r] * rl[jt]);
            int j = j0 + jt * 16 + l16;
            *(us4*)&ctxT[((size_t)b * N_ + j) * MID_ + wave * 32 + ct * 16 + quad * 4] = pk;
        }
    }
}

// ---------------------------------------------------------------------------
// out_gemm (MFMA): out[b,co,n] = x + bo[co] + sum_m wo[co,m]*ctxT[b,n,m]
// ---------------------------------------------------------------------------
__global__ __launch_bounds__(256) void out_gemm_kernel(
    const float* __restrict__ wo, const float* __restrict__ bo,
    const unsigned short* __restrict__ ctxT, const float* __restrict__ x,
    float* __restrict__ out)
{
    const int b   = blockIdx.z;
    const int n0  = blockIdx.x * 128;
    const int co0 = blockIdx.y * 128;

    __shared__ unsigned short Wos[128][72];
    __shared__ unsigned short Cs[128][72];
    __shared__ float bo_s[128];

    const int tid  = threadIdx.x;
    const int wave = tid >> 6;
    const int lane = tid & 63;
    const int quad = lane >> 4;
    const int l16  = lane & 15;
    const int wi   = wave >> 1;
    const int wj   = wave & 1;

    if (tid < 128) bo_s[tid] = bo[co0 + tid];

    f32x4 acc[4][4];
    #pragma unroll
    for (int it = 0; it < 4; it++)
        #pragma unroll
        for (int jt = 0; jt < 4; jt++)
            #pragma unroll
            for (int r = 0; r < 4; r++) acc[it][jt][r] = 0.0f;

    const int srow  = tid >> 1;
    const int shalf = (tid & 1) * 32;

    for (int k0 = 0; k0 < MID_; k0 += 64) {
        __syncthreads();
        #pragma unroll
        for (int i = 0; i < 4; i++) {
            float4 f0 = *(const float4*)&wo[(size_t)(co0 + srow) * MID_ + k0 + shalf + 8 * i];
            float4 f1 = *(const float4*)&wo[(size_t)(co0 + srow) * MID_ + k0 + shalf + 8 * i + 4];
            *(us8*)&Wos[srow][shalf + 8 * i] = pack8(f0, f1);
            *(us8*)&Cs[srow][shalf + 8 * i] =
                *(const us8*)&ctxT[((size_t)b * N_ + n0 + srow) * MID_ + k0 + shalf + 8 * i];
        }
        __syncthreads();
        #pragma unroll
        for (int cl = 0; cl < 64; cl += 32) {
            bf16x8 af[4], bfr[4];
            #pragma unroll
            for (int t = 0; t < 4; t++)
                af[t] = *(const bf16x8*)&Wos[wi * 64 + t * 16 + l16][cl + quad * 8];
            #pragma unroll
            for (int t = 0; t < 4; t++)
                bfr[t] = *(const bf16x8*)&Cs[wj * 64 + t * 16 + l16][cl + quad * 8];
            #pragma unroll
            for (int it = 0; it < 4; it++)
                #pragma unroll
                for (int jt = 0; jt < 4; jt++)
                    acc[it][jt] = __builtin_amdgcn_mfma_f32_16x16x32_bf16(
                        af[it], bfr[jt], acc[it][jt], 0, 0, 0);
        }
    }
    __syncthreads();

    #pragma unroll
    for (int it = 0; it < 4; it++) {
        #pragma unroll
        for (int r = 0; r < 4; r++) {
            int col = wi * 64 + it * 16 + quad * 4 + r;
            int co = co0 + col;
            float bias = bo_s[col];
            #pragma unroll
            for (int jt = 0; jt < 4; jt++) {
                int n = n0 + wj * 64 + jt * 16 + l16;
                size_t a = ((size_t)b * C_ + co) * N_ + n;
                out[a] = acc[it][jt][r] + bias + x[a];
            }
        }
    }
}

extern "C" void kernel_launch(void* const* d_in, const int* in_sizes, int n_in,
                              void* d_out, int out_size, void* d_ws, size_t ws_size,
                              hipStream_t stream) {
    const float* x     = (const float*)d_in[0];
    const float* wq    = (const float*)d_in[1];
    const float* bq    = (const float*)d_in[2];
    const float* gq    = (const float*)d_in[3];
    const float* betaq = (const float*)d_in[4];
    const float* wk    = (const float*)d_in[5];
    const float* bk    = (const float*)d_in[6];
    const float* gk    = (const float*)d_in[7];
    const float* betak = (const float*)d_in[8];
    const float* wv    = (const float*)d_in[9];
    const float* bv    = (const float*)d_in[10];
    const float* wo    = (const float*)d_in[11];
    const float* bo    = (const float*)d_in[12];
    const float* mq    = (const float*)d_in[13];
    const float* vq    = (const float*)d_in[14];
    const float* mk    = (const float*)d_in[15];
    const float* vk    = (const float*)d_in[16];
    float* out = (float*)d_out;

    const size_t elems = (size_t)B_ * MID_ * N_;   // 8,388,608
    unsigned short* qt   = (unsigned short*)d_ws;  // [B][N][MID]
    unsigned short* kt   = qt + elems;             // [B][N][MID]
    unsigned short* v    = kt + elems;             // [B][MID][N]
    unsigned short* ctxT = v + elems;              // [B][N][MID]
    // workspace: 64 MiB

    // d_out doubles as scratch; dead before out_gemm writes the real output:
    unsigned short* xt = (unsigned short*)d_out;          // [B][N][C] = 32 MiB
    unsigned short* wb = xt + (size_t)B_ * N_ * C_;       // [3][256][512] = 768 KiB

    prep_x_kernel<<<dim3(N_ / 64, C_ / 64, B_), 256, 0, stream>>>(x, xt);
    prep_w_kernel<<<dim3(96), 256, 0, stream>>>(wq, wk, wv, wb);

    qkv_gemm_kernel<<<dim3(N_ / 128, MID_ / 128, B_ * 3), 256, 0, stream>>>(
        xt, wb, bq, gq, betaq, mq, vq, bk, gk, betak, mk, vk, bv, qt, kt, v);

    flash_kernel<<<dim3(N_ / 64, B_), 512, 0, stream>>>(qt, kt, v, ctxT);

    out_gemm_kernel<<<dim3(N_ / 128, C_ / 128, B_), 256, 0, stream>>>(
        wo, bo, ctxT, x, out);
}